// Round 11
// baseline (232.087 us; speedup 1.0000x reference)
//
#include <hip/hip_runtime.h>
#include <hip/hip_bf16.h>

// Problem constants: B=4, L=2048, H=8, D=64, SAMPLE_K=N_TOP=40
#define BB 4
#define LL 2048
#define HH 8
#define DD 64
#define SK 40
#define NT 40
#define CH 256              // keys per attn chunk
#define NCH (LL / CH)       // 8 chunks per (b,h)
#define QH 20               // queries per attn block (40 split in 2)

typedef float f4 __attribute__((ext_vector_type(4)));

// ---------------------------------------------------------------------------
// Kernel 1: M[bh][l] = max_s(q . k_{idx[l,s]}) - (sum_s q . k_{idx[l,s]}) / L
//
// Round 24. Post-mortems: r10's phase-split+nontemporal destroyed cache reuse
// (FETCH 56->140MB, WRITE ->100MB, HBM-bound, 76us) — both reverted. r8's
// 42.4us decomposes as TA/TCP line-touch service: its loads (voff=lane*32,
// offset 0/16) put lanes at 32B stride -> each dwordx4 touches all 32 lines
// of the 2KB row using 16B of each = 64 touches/row (2x minimum); 32 waves x
// 80 instr x 32 lines ~ 82k touches/CU ~ 34us at ~1 line/cy. This round:
// CONTIGUOUS instructions. Instr A = first 1KB at lane*16 (16 lines, fully
// used), instr B = second 1KB at 1024+lane*16. 32 touches/row — optimal.
// Lane holds 4 dims of head lane>>4 (A) and 4 dims of head 4+(lane>>4) (B);
// per sample: 8 FMA + two 16-lane shfl_xor{1,2,4,8} reduces (8 shfls, DS ~6us
// /CU, hidden under vmem). Same 40-sample/wave rolling pipeline as r8:
// 8 register pairs, 16 loads in flight, vmcnt(14) steady, 14..0 tail.
// No LDS, no barriers, no phasing, no nt hints.
// ---------------------------------------------------------------------------
__global__ __launch_bounds__(256, 4) void compute_m_kernel(
        const float* __restrict__ Q, const float* __restrict__ K,
        const int* __restrict__ idx, float* __restrict__ M) {
    int blk = blockIdx.x;
    int x = blk & 7, g = blk >> 3;
    int b = x >> 1;                    // 2 XCDs per batch (K ~4.2MB)
    int lg = (g << 1) | (x & 1);       // l-group [0,512)
    int t = threadIdx.x;
    int lane = t & 63, w = t >> 6;
    int l = lg * 4 + w;                // this wave's l

    // Q fragments, identity map with the two row halves:
    // qf0 = floats [lane*4,+4)      -> head lane>>4,     dims 4*(lane&15)..
    // qf1 = floats [256+lane*4,+4)  -> head 4+(lane>>4), dims 4*(lane&15)..
    const f4* q0p = (const f4*)(Q + ((size_t)b * LL + l) * 512 + lane * 4);
    const f4* q1p = (const f4*)(Q + ((size_t)b * LL + l) * 512 + 256 + lane * 4);
    f4 qf0 = *q0p, qf1 = *q1p;

    // idx row: coalesced read by lanes 0..39, broadcast via readlane
    int myidx = 0;
    if (lane < SK) myidx = idx[(size_t)l * SK + lane];

    const float* Kb8 = K + (size_t)b * LL * 512;
    int voff0 = lane * 16;             // first 1KB of row, contiguous
    int voff1 = lane * 16 + 1024;      // second 1KB, contiguous

    // Drain compiler-tracked loads (Q, idx) before the asm pipeline.
    asm volatile("" : "+v"(qf0), "+v"(qf1));

    f4 A0, B0, A1, B1, A2, B2, A3, B3, A4, B4, A5, B5, A6, B6, A7, B7;

    #define PTRK(k) (Kb8 + (size_t)__builtin_amdgcn_readlane(myidx, (k)) * 512)
    #define IS(AV, BV, k)                                                       \
        asm volatile("global_load_dwordx4 %0, %2, %4\n\t"                       \
                     "global_load_dwordx4 %1, %3, %4"                           \
                     : "=&v"(AV), "=&v"(BV)                                     \
                     : "v"(voff0), "v"(voff1), "s"(PTRK(k)))

    float mx0 = -INFINITY, sm0 = 0.0f, mx1 = -INFINITY, sm1 = 0.0f;

    #define CO(AV, BV, WAIT) do {                                               \
        asm volatile(WAIT : "+v"(AV), "+v"(BV));                                \
        float p0 = qf0.x*AV.x + qf0.y*AV.y + qf0.z*AV.z + qf0.w*AV.w;           \
        float p1 = qf1.x*BV.x + qf1.y*BV.y + qf1.z*BV.z + qf1.w*BV.w;           \
        p0 += __shfl_xor(p0, 1, 64);  p1 += __shfl_xor(p1, 1, 64);              \
        p0 += __shfl_xor(p0, 2, 64);  p1 += __shfl_xor(p1, 2, 64);              \
        p0 += __shfl_xor(p0, 4, 64);  p1 += __shfl_xor(p1, 4, 64);              \
        p0 += __shfl_xor(p0, 8, 64);  p1 += __shfl_xor(p1, 8, 64);              \
        mx0 = fmaxf(mx0, p0); sm0 += p0;                                        \
        mx1 = fmaxf(mx1, p1); sm1 += p1;                                        \
    } while (0)

    // prologue: samples 0..7 (16 loads in flight)
    IS(A0, B0, 0); IS(A1, B1, 1); IS(A2, B2, 2); IS(A3, B3, 3);
    IS(A4, B4, 4); IS(A5, B5, 5); IS(A6, B6, 6); IS(A7, B7, 7);
    // steady: consume sample s (pair s&7), issue sample s+8
    CO(A0, B0, "s_waitcnt vmcnt(14)"); IS(A0, B0,  8);
    CO(A1, B1, "s_waitcnt vmcnt(14)"); IS(A1, B1,  9);
    CO(A2, B2, "s_waitcnt vmcnt(14)"); IS(A2, B2, 10);
    CO(A3, B3, "s_waitcnt vmcnt(14)"); IS(A3, B3, 11);
    CO(A4, B4, "s_waitcnt vmcnt(14)"); IS(A4, B4, 12);
    CO(A5, B5, "s_waitcnt vmcnt(14)"); IS(A5, B5, 13);
    CO(A6, B6, "s_waitcnt vmcnt(14)"); IS(A6, B6, 14);
    CO(A7, B7, "s_waitcnt vmcnt(14)"); IS(A7, B7, 15);
    CO(A0, B0, "s_waitcnt vmcnt(14)"); IS(A0, B0, 16);
    CO(A1, B1, "s_waitcnt vmcnt(14)"); IS(A1, B1, 17);
    CO(A2, B2, "s_waitcnt vmcnt(14)"); IS(A2, B2, 18);
    CO(A3, B3, "s_waitcnt vmcnt(14)"); IS(A3, B3, 19);
    CO(A4, B4, "s_waitcnt vmcnt(14)"); IS(A4, B4, 20);
    CO(A5, B5, "s_waitcnt vmcnt(14)"); IS(A5, B5, 21);
    CO(A6, B6, "s_waitcnt vmcnt(14)"); IS(A6, B6, 22);
    CO(A7, B7, "s_waitcnt vmcnt(14)"); IS(A7, B7, 23);
    CO(A0, B0, "s_waitcnt vmcnt(14)"); IS(A0, B0, 24);
    CO(A1, B1, "s_waitcnt vmcnt(14)"); IS(A1, B1, 25);
    CO(A2, B2, "s_waitcnt vmcnt(14)"); IS(A2, B2, 26);
    CO(A3, B3, "s_waitcnt vmcnt(14)"); IS(A3, B3, 27);
    CO(A4, B4, "s_waitcnt vmcnt(14)"); IS(A4, B4, 28);
    CO(A5, B5, "s_waitcnt vmcnt(14)"); IS(A5, B5, 29);
    CO(A6, B6, "s_waitcnt vmcnt(14)"); IS(A6, B6, 30);
    CO(A7, B7, "s_waitcnt vmcnt(14)"); IS(A7, B7, 31);
    CO(A0, B0, "s_waitcnt vmcnt(14)"); IS(A0, B0, 32);
    CO(A1, B1, "s_waitcnt vmcnt(14)"); IS(A1, B1, 33);
    CO(A2, B2, "s_waitcnt vmcnt(14)"); IS(A2, B2, 34);
    CO(A3, B3, "s_waitcnt vmcnt(14)"); IS(A3, B3, 35);
    CO(A4, B4, "s_waitcnt vmcnt(14)"); IS(A4, B4, 36);
    CO(A5, B5, "s_waitcnt vmcnt(14)"); IS(A5, B5, 37);
    CO(A6, B6, "s_waitcnt vmcnt(14)"); IS(A6, B6, 38);
    CO(A7, B7, "s_waitcnt vmcnt(14)"); IS(A7, B7, 39);
    // tail: consume samples 32..39, draining 16..0
    CO(A0, B0, "s_waitcnt vmcnt(14)");
    CO(A1, B1, "s_waitcnt vmcnt(12)");
    CO(A2, B2, "s_waitcnt vmcnt(10)");
    CO(A3, B3, "s_waitcnt vmcnt(8)");
    CO(A4, B4, "s_waitcnt vmcnt(6)");
    CO(A5, B5, "s_waitcnt vmcnt(4)");
    CO(A6, B6, "s_waitcnt vmcnt(2)");
    CO(A7, B7, "s_waitcnt vmcnt(0)");
    #undef IS
    #undef CO
    #undef PTRK

    // leaders (lane&15)==0: head lane>>4 from mx0/sm0, head +4 from mx1/sm1
    if ((lane & 15) == 0) {
        int h0 = lane >> 4;
        M[((size_t)b * HH + h0) * LL + l]     = mx0 - sm0 * (1.0f / (float)LL);
        M[((size_t)b * HH + h0 + 4) * LL + l] = mx1 - sm1 * (1.0f / (float)LL);
    }
}

// ---------------------------------------------------------------------------
// Kernel 2: top-40 per (b,h), lower index wins ties. Incremental argmax.
// ---------------------------------------------------------------------------
__global__ __launch_bounds__(256) void topk_kernel(const float* __restrict__ M,
                                                   int* __restrict__ topi) {
    __shared__ unsigned long long keys[LL];   // 16 KB
    __shared__ unsigned long long wmax[4];
    __shared__ int win;
    int bh = blockIdx.x;
    int t  = threadIdx.x;
    int lane = t & 63, w = t >> 6;

    unsigned long long kmax = 0ULL;
    #pragma unroll
    for (int j = 0; j < 8; ++j) {
        int i = t + 256 * j;
        unsigned int bits = __float_as_uint(M[(size_t)bh * LL + i]);
        bits = (bits & 0x80000000u) ? ~bits : (bits | 0x80000000u);
        unsigned long long k = ((unsigned long long)bits << 11)
                             | (unsigned int)(LL - 1 - i);
        keys[i] = k;
        if (k > kmax) kmax = k;
    }
    __syncthreads();

    for (int u = 0; u < NT; ++u) {
        unsigned long long k = kmax;
        #pragma unroll
        for (int off = 32; off >= 1; off >>= 1) {
            unsigned long long o = __shfl_xor(k, off, 64);
            if (o > k) k = o;
        }
        if (lane == 0) wmax[w] = k;
        __syncthreads();
        if (t == 0) {
            unsigned long long k0 = wmax[0];
            if (wmax[1] > k0) k0 = wmax[1];
            if (wmax[2] > k0) k0 = wmax[2];
            if (wmax[3] > k0) k0 = wmax[3];
            int i = (LL - 1) - (int)(k0 & 0x7FF);
            topi[bh * NT + u] = i;
            keys[i] = 0ULL;
            win = i;
        }
        __syncthreads();
        if ((win & 255) == t) {          // only the owner rescans
            kmax = 0ULL;
            #pragma unroll
            for (int j = 0; j < 8; ++j) {
                unsigned long long kk = keys[t + 256 * j];
                if (kk > kmax) kmax = kk;
            }
        }
    }
}

// ---------------------------------------------------------------------------
// Kernel 3: flash-chunked attention, query-split.
// __launch_bounds__(256,3) keeps kreg/vcol in registers (round 7 spill fix).
// (m,l) packed float2 store (round 8 granule-waste fix).
// ---------------------------------------------------------------------------
__global__ __launch_bounds__(256, 3) void attn_kernel(
        const float* __restrict__ Q, const float* __restrict__ K,
        const float* __restrict__ V, const int* __restrict__ topi,
        float2* __restrict__ pml, float* __restrict__ po) {
    __shared__ float  qs[QH][DD];        //  5120 B
    __shared__ float4 e4buf[4][64];      //  4096 B
    __shared__ float  oarea[4][QH][DD];  // 20480 B
    __shared__ float  mlarea[4][QH][2];  //   640 B

    int blk = blockIdx.x;
    int qh  = blk >> 8;                  // 0/1 query half
    int cc2 = blk & 255;
    int c   = cc2 & (NCH - 1);
    int bh  = cc2 >> 3;
    int h = bh & (HH - 1), b = bh >> 3;
    int t = threadIdx.x, lane = t & 63, w = t >> 6;
    int u0 = qh * QH;

    for (int i = t; i < QH * DD; i += 256) {
        int u = i >> 6, d = i & 63;
        int lq = topi[bh * NT + u0 + u];
        qs[u][d] = Q[(((size_t)b * LL + lq) * HH + h) * DD + d];
    }

    int key = c * CH + w * 64 + lane;
    const float4* kr = (const float4*)&K[(((size_t)b * LL + key) * HH + h) * DD];
    float4 kreg[16];
    #pragma unroll
    for (int j = 0; j < 16; ++j) kreg[j] = kr[j];

    float vcol[64];
    const float* vb = &V[(((size_t)b * LL + c * CH + w * 64) * HH + h) * DD + lane];
    #pragma unroll
    for (int j = 0; j < 64; ++j) vcol[j] = vb[(size_t)j * HH * DD];

    __syncthreads();   // qs ready

    for (int uq = 0; uq < QH / 4; ++uq) {
        float o0 = 0, o1 = 0, o2 = 0, o3 = 0;
        float mv0, mv1, mv2, mv3, lv0, lv1, lv2, lv3;
        float4 ev;
        #pragma unroll
        for (int j = 0; j < 4; ++j) {
            int u = uq * 4 + j;
            const float4* q4 = (const float4*)&qs[u][0];
            float s = 0.0f;
            #pragma unroll
            for (int cc = 0; cc < 16; ++cc) {
                float4 qv = q4[cc];
                s += qv.x * kreg[cc].x + qv.y * kreg[cc].y
                   + qv.z * kreg[cc].z + qv.w * kreg[cc].w;
            }
            s *= 0.125f;   // 1/sqrt(64)
            float m = s;
            #pragma unroll
            for (int off = 32; off >= 1; off >>= 1)
                m = fmaxf(m, __shfl_xor(m, off, 64));
            float e = __expf(s - m);
            float ls = e;
            #pragma unroll
            for (int off = 32; off >= 1; off >>= 1)
                ls += __shfl_xor(ls, off, 64);
            if (j == 0) { mv0 = m; lv0 = ls; ev.x = e; }
            if (j == 1) { mv1 = m; lv1 = ls; ev.y = e; }
            if (j == 2) { mv2 = m; lv2 = ls; ev.z = e; }
            if (j == 3) { mv3 = m; lv3 = ls; ev.w = e; }
        }
        e4buf[w][lane] = ev;
        asm volatile("s_waitcnt lgkmcnt(0)" ::: "memory");
        #pragma unroll
        for (int l2 = 0; l2 < 64; ++l2) {      // FULL unroll: vcol static
            float4 e = e4buf[w][l2];
            float  v = vcol[l2];
            o0 += e.x * v; o1 += e.y * v; o2 += e.z * v; o3 += e.w * v;
        }
        oarea[w][uq * 4 + 0][lane] = o0;
        oarea[w][uq * 4 + 1][lane] = o1;
        oarea[w][uq * 4 + 2][lane] = o2;
        oarea[w][uq * 4 + 3][lane] = o3;
        if (lane == 0) {
            mlarea[w][uq * 4 + 0][0] = mv0; mlarea[w][uq * 4 + 0][1] = lv0;
            mlarea[w][uq * 4 + 1][0] = mv1; mlarea[w][uq * 4 + 1][1] = lv1;
            mlarea[w][uq * 4 + 2][0] = mv2; mlarea[w][uq * 4 + 2][1] = lv2;
            mlarea[w][uq * 4 + 3][0] = mv3; mlarea[w][uq * 4 + 3][1] = lv3;
        }
    }
    __syncthreads();

    for (int i = t; i < QH * DD; i += 256) {
        int u = i >> 6, d = i & 63;
        float m0 = mlarea[0][u][0], m1 = mlarea[1][u][0];
        float m2 = mlarea[2][u][0], m3 = mlarea[3][u][0];
        float mb = fmaxf(fmaxf(m0, m1), fmaxf(m2, m3));
        float s0 = __expf(m0 - mb), s1 = __expf(m1 - mb);
        float s2 = __expf(m2 - mb), s3 = __expf(m3 - mb);
        float ob = oarea[0][u][d] * s0 + oarea[1][u][d] * s1
                 + oarea[2][u][d] * s2 + oarea[3][u][d] * s3;
        int gu = u0 + u;
        po[((size_t)(bh * NT + gu) * NCH + c) * DD + d] = ob;
        if (d == 0) {
            float lb = mlarea[0][u][1] * s0 + mlarea[1][u][1] * s1
                     + mlarea[2][u][1] * s2 + mlarea[3][u][1] * s3;
            pml[(bh * NT + gu) * NCH + c] = make_float2(mb, lb);
        }
    }
}

// ---------------------------------------------------------------------------
// Kernel 4: merge chunk partials. One wave per (bh,u), lane = d.
// ---------------------------------------------------------------------------
__global__ __launch_bounds__(256) void merge_kernel(
        const float2* __restrict__ pml, const float* __restrict__ po,
        float* __restrict__ out) {
    int wid  = blockIdx.x * 4 + (threadIdx.x >> 6);
    int lane = threadIdx.x & 63;
    int u  = wid % NT;
    int bh = wid / NT;
    int h = bh & (HH - 1), b = bh >> 3;
    int base = (bh * NT + u) * NCH;

    float m = -INFINITY;
    #pragma unroll
    for (int cc = 0; cc < NCH; ++cc) m = fmaxf(m, pml[base + cc].x);
    float lsum = 0.0f, o = 0.0f;
    #pragma unroll
    for (int cc = 0; cc < NCH; ++cc) {
        float2 ml = pml[base + cc];
        float sc = __expf(ml.x - m);
        lsum += ml.y * sc;
        o    += po[(size_t)(base + cc) * DD + lane] * sc;
    }
    out[(((size_t)b * NT + u) * HH + h) * DD + lane] = o / lsum;
}

extern "C" void kernel_launch(void* const* d_in, const int* in_sizes, int n_in,
                              void* d_out, int out_size, void* d_ws, size_t ws_size,
                              hipStream_t stream) {
    const float* Q   = (const float*)d_in[0];
    const float* K   = (const float*)d_in[1];
    const float* V   = (const float*)d_in[2];
    const int*   idx = (const int*)d_in[3];
    float* out = (float*)d_out;

    char* ws = (char*)d_ws;
    float*  M    = (float*)ws;                        ws += (size_t)BB * HH * LL * sizeof(float);
    int*    topi = (int*)ws;                          ws += (size_t)BB * HH * NT * sizeof(int);
    float2* pml  = (float2*)ws;                       ws += (size_t)BB * HH * NT * NCH * sizeof(float2);
    float*  po   = (float*)ws;                        // 2.62 MB

    hipLaunchKernelGGL(compute_m_kernel, dim3(BB * LL / 4), dim3(256), 0, stream,
                       Q, K, idx, M);
    hipLaunchKernelGGL(topk_kernel, dim3(BB * HH), dim3(256), 0, stream, M, topi);
    hipLaunchKernelGGL(attn_kernel, dim3(2 * BB * HH * NCH), dim3(256), 0, stream,
                       Q, K, V, topi, pml, po);
    hipLaunchKernelGGL(merge_kernel, dim3(BB * HH * NT / 4), dim3(256), 0, stream,
                       pml, po, out);
}

// Round 12
// 202.245 us; speedup vs baseline: 1.1476x; 1.1476x over previous
//
#include <hip/hip_runtime.h>
#include <hip/hip_bf16.h>

// Problem constants: B=4, L=2048, H=8, D=64, SAMPLE_K=N_TOP=40
#define BB 4
#define LL 2048
#define HH 8
#define DD 64
#define SK 40
#define NT 40
#define CH 256              // keys per attn chunk
#define NCH (LL / CH)       // 8 chunks per (b,h)
#define QH 20               // queries per attn block (40 split in 2)

typedef float f4 __attribute__((ext_vector_type(4)));

// ---------------------------------------------------------------------------
// Kernel 1: M[bh][l] = max_s(q . k_{idx[l,s]}) - (sum_s q . k_{idx[l,s]}) / L
//
// Round 25. r11 post-mortem: WRITE_SIZE=170MB exposed SCRATCH SPILL of the
// 16-f4 forced-live asm set (RA stuck at 64 VGPRs, spilled instead of
// growing) — r10/r11 regressions were spill-driven, so L2-phasing never got
// a clean test. The non-spilling variants all sit at 42us = 655MB gather /
// ~15TB/s L3 (L2 can't hold batch-K 4.2MB + Q stream; FETCH ~50MB = only
// true HBM misses). This round: half-row TIME PHASING with a SPILL-PROOF
// live set. Phase p gathers only bytes [p*1KB, +1KB) of each sampled row:
// per-XCD live set 2.1MB < 4MB L2, and all 2048 blocks are co-resident
// (8 blocks/CU) -> phase-coherent population -> gather served from L2.
//   - depth-6 rolling pipeline, ONE dwordx4/sample (lane's 16B at lane*16
//     within the half; contiguous 1KB per instruction, 16 fully-used lines);
//   - lane holds dims [4*(lane&15),+4) of head (lane>>4)+4p; 4 FMA + 4
//     shfl_xor{1,2,4,8} per sample (16-lane head groups);
//   - live VGPRs: 6 f4 + qf0/qf1 + addrs ~ 60 total << 128 cap -> no spill;
//   - Q nontemporal (pure stream, keep out of L2); K plain; phases strictly
//     separated (phase 0 drains vmcnt(0) before phase 1 issues).
// ---------------------------------------------------------------------------
__global__ __launch_bounds__(256, 4) void compute_m_kernel(
        const float* __restrict__ Q, const float* __restrict__ K,
        const int* __restrict__ idx, float* __restrict__ M) {
    int blk = blockIdx.x;
    int x = blk & 7, g = blk >> 3;
    int b = x >> 1;                    // 2 XCDs per batch
    int lg = (g << 1) | (x & 1);       // l-group [0,512)
    int t = threadIdx.x;
    int lane = t & 63, w = t >> 6;
    int l = lg * 4 + w;                // this wave's l

    // Q fragments, identity map with the two row halves (nontemporal stream)
    const f4* q0p = (const f4*)(Q + ((size_t)b * LL + l) * 512 + lane * 4);
    const f4* q1p = (const f4*)(Q + ((size_t)b * LL + l) * 512 + 256 + lane * 4);
    f4 qf0 = __builtin_nontemporal_load(q0p);
    f4 qf1 = __builtin_nontemporal_load(q1p);

    // idx row: coalesced read by lanes 0..39, broadcast via readlane
    int myidx = 0;
    if (lane < SK) myidx = idx[(size_t)l * SK + lane];

    const float* Kb8 = K + (size_t)b * LL * 512;
    int voff0 = lane * 16;             // lane's 16B in half 0 (contiguous 1KB)
    int voff1 = lane * 16 + 1024;      // ... in half 1

    // Drain compiler-tracked loads (Q, idx) before the asm pipeline.
    asm volatile("" : "+v"(qf0), "+v"(qf1));

    f4 R0, R1, R2, R3, R4, R5;

    #define PTRK(k) (Kb8 + (size_t)__builtin_amdgcn_readlane(myidx, (k)) * 512)
    #define IS(RV, k, VO)                                                       \
        asm volatile("global_load_dwordx4 %0, %1, %2"                           \
                     : "=&v"(RV) : "v"(VO), "s"(PTRK(k)))

    float mx0 = -INFINITY, sm0 = 0.0f, mx1 = -INFINITY, sm1 = 0.0f;

    #define CO(RV, QF, MX, SM, WAIT) do {                                       \
        asm volatile(WAIT : "+v"(RV));                                          \
        float p = QF.x*RV.x + QF.y*RV.y + QF.z*RV.z + QF.w*RV.w;                \
        p += __shfl_xor(p, 1, 64);                                              \
        p += __shfl_xor(p, 2, 64);                                              \
        p += __shfl_xor(p, 4, 64);                                              \
        p += __shfl_xor(p, 8, 64);                                              \
        MX = fmaxf(MX, p);                                                      \
        SM += p;                                                                \
    } while (0)

    #define STEP(RV, QF, MX, SM, NXT, VO)                                       \
        CO(RV, QF, MX, SM, "s_waitcnt vmcnt(5)"); IS(RV, NXT, VO)

    // ---------------- phase 0: first halves, heads 0-3 ----------------
    IS(R0, 0, voff0); IS(R1, 1, voff0); IS(R2, 2, voff0);
    IS(R3, 3, voff0); IS(R4, 4, voff0); IS(R5, 5, voff0);
    STEP(R0, qf0, mx0, sm0,  6, voff0); STEP(R1, qf0, mx0, sm0,  7, voff0);
    STEP(R2, qf0, mx0, sm0,  8, voff0); STEP(R3, qf0, mx0, sm0,  9, voff0);
    STEP(R4, qf0, mx0, sm0, 10, voff0); STEP(R5, qf0, mx0, sm0, 11, voff0);
    STEP(R0, qf0, mx0, sm0, 12, voff0); STEP(R1, qf0, mx0, sm0, 13, voff0);
    STEP(R2, qf0, mx0, sm0, 14, voff0); STEP(R3, qf0, mx0, sm0, 15, voff0);
    STEP(R4, qf0, mx0, sm0, 16, voff0); STEP(R5, qf0, mx0, sm0, 17, voff0);
    STEP(R0, qf0, mx0, sm0, 18, voff0); STEP(R1, qf0, mx0, sm0, 19, voff0);
    STEP(R2, qf0, mx0, sm0, 20, voff0); STEP(R3, qf0, mx0, sm0, 21, voff0);
    STEP(R4, qf0, mx0, sm0, 22, voff0); STEP(R5, qf0, mx0, sm0, 23, voff0);
    STEP(R0, qf0, mx0, sm0, 24, voff0); STEP(R1, qf0, mx0, sm0, 25, voff0);
    STEP(R2, qf0, mx0, sm0, 26, voff0); STEP(R3, qf0, mx0, sm0, 27, voff0);
    STEP(R4, qf0, mx0, sm0, 28, voff0); STEP(R5, qf0, mx0, sm0, 29, voff0);
    STEP(R0, qf0, mx0, sm0, 30, voff0); STEP(R1, qf0, mx0, sm0, 31, voff0);
    STEP(R2, qf0, mx0, sm0, 32, voff0); STEP(R3, qf0, mx0, sm0, 33, voff0);
    STEP(R4, qf0, mx0, sm0, 34, voff0); STEP(R5, qf0, mx0, sm0, 35, voff0);
    STEP(R0, qf0, mx0, sm0, 36, voff0); STEP(R1, qf0, mx0, sm0, 37, voff0);
    STEP(R2, qf0, mx0, sm0, 38, voff0); STEP(R3, qf0, mx0, sm0, 39, voff0);
    // drain: outstanding samples 34..39 in R4,R5,R0,R1,R2,R3
    CO(R4, qf0, mx0, sm0, "s_waitcnt vmcnt(5)");
    CO(R5, qf0, mx0, sm0, "s_waitcnt vmcnt(4)");
    CO(R0, qf0, mx0, sm0, "s_waitcnt vmcnt(3)");
    CO(R1, qf0, mx0, sm0, "s_waitcnt vmcnt(2)");
    CO(R2, qf0, mx0, sm0, "s_waitcnt vmcnt(1)");
    CO(R3, qf0, mx0, sm0, "s_waitcnt vmcnt(0)");

    // ---------------- phase 1: second halves, heads 4-7 ----------------
    IS(R0, 0, voff1); IS(R1, 1, voff1); IS(R2, 2, voff1);
    IS(R3, 3, voff1); IS(R4, 4, voff1); IS(R5, 5, voff1);
    STEP(R0, qf1, mx1, sm1,  6, voff1); STEP(R1, qf1, mx1, sm1,  7, voff1);
    STEP(R2, qf1, mx1, sm1,  8, voff1); STEP(R3, qf1, mx1, sm1,  9, voff1);
    STEP(R4, qf1, mx1, sm1, 10, voff1); STEP(R5, qf1, mx1, sm1, 11, voff1);
    STEP(R0, qf1, mx1, sm1, 12, voff1); STEP(R1, qf1, mx1, sm1, 13, voff1);
    STEP(R2, qf1, mx1, sm1, 14, voff1); STEP(R3, qf1, mx1, sm1, 15, voff1);
    STEP(R4, qf1, mx1, sm1, 16, voff1); STEP(R5, qf1, mx1, sm1, 17, voff1);
    STEP(R0, qf1, mx1, sm1, 18, voff1); STEP(R1, qf1, mx1, sm1, 19, voff1);
    STEP(R2, qf1, mx1, sm1, 20, voff1); STEP(R3, qf1, mx1, sm1, 21, voff1);
    STEP(R4, qf1, mx1, sm1, 22, voff1); STEP(R5, qf1, mx1, sm1, 23, voff1);
    STEP(R0, qf1, mx1, sm1, 24, voff1); STEP(R1, qf1, mx1, sm1, 25, voff1);
    STEP(R2, qf1, mx1, sm1, 26, voff1); STEP(R3, qf1, mx1, sm1, 27, voff1);
    STEP(R4, qf1, mx1, sm1, 28, voff1); STEP(R5, qf1, mx1, sm1, 29, voff1);
    STEP(R0, qf1, mx1, sm1, 30, voff1); STEP(R1, qf1, mx1, sm1, 31, voff1);
    STEP(R2, qf1, mx1, sm1, 32, voff1); STEP(R3, qf1, mx1, sm1, 33, voff1);
    STEP(R4, qf1, mx1, sm1, 34, voff1); STEP(R5, qf1, mx1, sm1, 35, voff1);
    STEP(R0, qf1, mx1, sm1, 36, voff1); STEP(R1, qf1, mx1, sm1, 37, voff1);
    STEP(R2, qf1, mx1, sm1, 38, voff1); STEP(R3, qf1, mx1, sm1, 39, voff1);
    CO(R4, qf1, mx1, sm1, "s_waitcnt vmcnt(5)");
    CO(R5, qf1, mx1, sm1, "s_waitcnt vmcnt(4)");
    CO(R0, qf1, mx1, sm1, "s_waitcnt vmcnt(3)");
    CO(R1, qf1, mx1, sm1, "s_waitcnt vmcnt(2)");
    CO(R2, qf1, mx1, sm1, "s_waitcnt vmcnt(1)");
    CO(R3, qf1, mx1, sm1, "s_waitcnt vmcnt(0)");
    #undef IS
    #undef CO
    #undef STEP
    #undef PTRK

    // leaders (lane&15)==0: head lane>>4 from phase 0, head +4 from phase 1
    if ((lane & 15) == 0) {
        int h0 = lane >> 4;
        M[((size_t)b * HH + h0) * LL + l]     = mx0 - sm0 * (1.0f / (float)LL);
        M[((size_t)b * HH + h0 + 4) * LL + l] = mx1 - sm1 * (1.0f / (float)LL);
    }
}

// ---------------------------------------------------------------------------
// Kernel 2: top-40 per (b,h), lower index wins ties. Incremental argmax.
// ---------------------------------------------------------------------------
__global__ __launch_bounds__(256) void topk_kernel(const float* __restrict__ M,
                                                   int* __restrict__ topi) {
    __shared__ unsigned long long keys[LL];   // 16 KB
    __shared__ unsigned long long wmax[4];
    __shared__ int win;
    int bh = blockIdx.x;
    int t  = threadIdx.x;
    int lane = t & 63, w = t >> 6;

    unsigned long long kmax = 0ULL;
    #pragma unroll
    for (int j = 0; j < 8; ++j) {
        int i = t + 256 * j;
        unsigned int bits = __float_as_uint(M[(size_t)bh * LL + i]);
        bits = (bits & 0x80000000u) ? ~bits : (bits | 0x80000000u);
        unsigned long long k = ((unsigned long long)bits << 11)
                             | (unsigned int)(LL - 1 - i);
        keys[i] = k;
        if (k > kmax) kmax = k;
    }
    __syncthreads();

    for (int u = 0; u < NT; ++u) {
        unsigned long long k = kmax;
        #pragma unroll
        for (int off = 32; off >= 1; off >>= 1) {
            unsigned long long o = __shfl_xor(k, off, 64);
            if (o > k) k = o;
        }
        if (lane == 0) wmax[w] = k;
        __syncthreads();
        if (t == 0) {
            unsigned long long k0 = wmax[0];
            if (wmax[1] > k0) k0 = wmax[1];
            if (wmax[2] > k0) k0 = wmax[2];
            if (wmax[3] > k0) k0 = wmax[3];
            int i = (LL - 1) - (int)(k0 & 0x7FF);
            topi[bh * NT + u] = i;
            keys[i] = 0ULL;
            win = i;
        }
        __syncthreads();
        if ((win & 255) == t) {          // only the owner rescans
            kmax = 0ULL;
            #pragma unroll
            for (int j = 0; j < 8; ++j) {
                unsigned long long kk = keys[t + 256 * j];
                if (kk > kmax) kmax = kk;
            }
        }
    }
}

// ---------------------------------------------------------------------------
// Kernel 3: flash-chunked attention, query-split.
// __launch_bounds__(256,3) keeps kreg/vcol in registers (round 7 spill fix).
// (m,l) packed float2 store (round 8 granule-waste fix).
// ---------------------------------------------------------------------------
__global__ __launch_bounds__(256, 3) void attn_kernel(
        const float* __restrict__ Q, const float* __restrict__ K,
        const float* __restrict__ V, const int* __restrict__ topi,
        float2* __restrict__ pml, float* __restrict__ po) {
    __shared__ float  qs[QH][DD];        //  5120 B
    __shared__ float4 e4buf[4][64];      //  4096 B
    __shared__ float  oarea[4][QH][DD];  // 20480 B
    __shared__ float  mlarea[4][QH][2];  //   640 B

    int blk = blockIdx.x;
    int qh  = blk >> 8;                  // 0/1 query half
    int cc2 = blk & 255;
    int c   = cc2 & (NCH - 1);
    int bh  = cc2 >> 3;
    int h = bh & (HH - 1), b = bh >> 3;
    int t = threadIdx.x, lane = t & 63, w = t >> 6;
    int u0 = qh * QH;

    for (int i = t; i < QH * DD; i += 256) {
        int u = i >> 6, d = i & 63;
        int lq = topi[bh * NT + u0 + u];
        qs[u][d] = Q[(((size_t)b * LL + lq) * HH + h) * DD + d];
    }

    int key = c * CH + w * 64 + lane;
    const float4* kr = (const float4*)&K[(((size_t)b * LL + key) * HH + h) * DD];
    float4 kreg[16];
    #pragma unroll
    for (int j = 0; j < 16; ++j) kreg[j] = kr[j];

    float vcol[64];
    const float* vb = &V[(((size_t)b * LL + c * CH + w * 64) * HH + h) * DD + lane];
    #pragma unroll
    for (int j = 0; j < 64; ++j) vcol[j] = vb[(size_t)j * HH * DD];

    __syncthreads();   // qs ready

    for (int uq = 0; uq < QH / 4; ++uq) {
        float o0 = 0, o1 = 0, o2 = 0, o3 = 0;
        float mv0, mv1, mv2, mv3, lv0, lv1, lv2, lv3;
        float4 ev;
        #pragma unroll
        for (int j = 0; j < 4; ++j) {
            int u = uq * 4 + j;
            const float4* q4 = (const float4*)&qs[u][0];
            float s = 0.0f;
            #pragma unroll
            for (int cc = 0; cc < 16; ++cc) {
                float4 qv = q4[cc];
                s += qv.x * kreg[cc].x + qv.y * kreg[cc].y
                   + qv.z * kreg[cc].z + qv.w * kreg[cc].w;
            }
            s *= 0.125f;   // 1/sqrt(64)
            float m = s;
            #pragma unroll
            for (int off = 32; off >= 1; off >>= 1)
                m = fmaxf(m, __shfl_xor(m, off, 64));
            float e = __expf(s - m);
            float ls = e;
            #pragma unroll
            for (int off = 32; off >= 1; off >>= 1)
                ls += __shfl_xor(ls, off, 64);
            if (j == 0) { mv0 = m; lv0 = ls; ev.x = e; }
            if (j == 1) { mv1 = m; lv1 = ls; ev.y = e; }
            if (j == 2) { mv2 = m; lv2 = ls; ev.z = e; }
            if (j == 3) { mv3 = m; lv3 = ls; ev.w = e; }
        }
        e4buf[w][lane] = ev;
        asm volatile("s_waitcnt lgkmcnt(0)" ::: "memory");
        #pragma unroll
        for (int l2 = 0; l2 < 64; ++l2) {      // FULL unroll: vcol static
            float4 e = e4buf[w][l2];
            float  v = vcol[l2];
            o0 += e.x * v; o1 += e.y * v; o2 += e.z * v; o3 += e.w * v;
        }
        oarea[w][uq * 4 + 0][lane] = o0;
        oarea[w][uq * 4 + 1][lane] = o1;
        oarea[w][uq * 4 + 2][lane] = o2;
        oarea[w][uq * 4 + 3][lane] = o3;
        if (lane == 0) {
            mlarea[w][uq * 4 + 0][0] = mv0; mlarea[w][uq * 4 + 0][1] = lv0;
            mlarea[w][uq * 4 + 1][0] = mv1; mlarea[w][uq * 4 + 1][1] = lv1;
            mlarea[w][uq * 4 + 2][0] = mv2; mlarea[w][uq * 4 + 2][1] = lv2;
            mlarea[w][uq * 4 + 3][0] = mv3; mlarea[w][uq * 4 + 3][1] = lv3;
        }
    }
    __syncthreads();

    for (int i = t; i < QH * DD; i += 256) {
        int u = i >> 6, d = i & 63;
        float m0 = mlarea[0][u][0], m1 = mlarea[1][u][0];
        float m2 = mlarea[2][u][0], m3 = mlarea[3][u][0];
        float mb = fmaxf(fmaxf(m0, m1), fmaxf(m2, m3));
        float s0 = __expf(m0 - mb), s1 = __expf(m1 - mb);
        float s2 = __expf(m2 - mb), s3 = __expf(m3 - mb);
        float ob = oarea[0][u][d] * s0 + oarea[1][u][d] * s1
                 + oarea[2][u][d] * s2 + oarea[3][u][d] * s3;
        int gu = u0 + u;
        po[((size_t)(bh * NT + gu) * NCH + c) * DD + d] = ob;
        if (d == 0) {
            float lb = mlarea[0][u][1] * s0 + mlarea[1][u][1] * s1
                     + mlarea[2][u][1] * s2 + mlarea[3][u][1] * s3;
            pml[(bh * NT + gu) * NCH + c] = make_float2(mb, lb);
        }
    }
}

// ---------------------------------------------------------------------------
// Kernel 4: merge chunk partials. One wave per (bh,u), lane = d.
// ---------------------------------------------------------------------------
__global__ __launch_bounds__(256) void merge_kernel(
        const float2* __restrict__ pml, const float* __restrict__ po,
        float* __restrict__ out) {
    int wid  = blockIdx.x * 4 + (threadIdx.x >> 6);
    int lane = threadIdx.x & 63;
    int u  = wid % NT;
    int bh = wid / NT;
    int h = bh & (HH - 1), b = bh >> 3;
    int base = (bh * NT + u) * NCH;

    float m = -INFINITY;
    #pragma unroll
    for (int cc = 0; cc < NCH; ++cc) m = fmaxf(m, pml[base + cc].x);
    float lsum = 0.0f, o = 0.0f;
    #pragma unroll
    for (int cc = 0; cc < NCH; ++cc) {
        float2 ml = pml[base + cc];
        float sc = __expf(ml.x - m);
        lsum += ml.y * sc;
        o    += po[(size_t)(base + cc) * DD + lane] * sc;
    }
    out[(((size_t)b * NT + u) * HH + h) * DD + lane] = o / lsum;
}

extern "C" void kernel_launch(void* const* d_in, const int* in_sizes, int n_in,
                              void* d_out, int out_size, void* d_ws, size_t ws_size,
                              hipStream_t stream) {
    const float* Q   = (const float*)d_in[0];
    const float* K   = (const float*)d_in[1];
    const float* V   = (const float*)d_in[2];
    const int*   idx = (const int*)d_in[3];
    float* out = (float*)d_out;

    char* ws = (char*)d_ws;
    float*  M    = (float*)ws;                        ws += (size_t)BB * HH * LL * sizeof(float);
    int*    topi = (int*)ws;                          ws += (size_t)BB * HH * NT * sizeof(int);
    float2* pml  = (float2*)ws;                       ws += (size_t)BB * HH * NT * NCH * sizeof(float2);
    float*  po   = (float*)ws;                        // 2.62 MB

    hipLaunchKernelGGL(compute_m_kernel, dim3(BB * LL / 4), dim3(256), 0, stream,
                       Q, K, idx, M);
    hipLaunchKernelGGL(topk_kernel, dim3(BB * HH), dim3(256), 0, stream, M, topi);
    hipLaunchKernelGGL(attn_kernel, dim3(2 * BB * HH * NCH), dim3(256), 0, stream,
                       Q, K, V, topi, pml, po);
    hipLaunchKernelGGL(merge_kernel, dim3(BB * HH * NT / 4), dim3(256), 0, stream,
                       pml, po, out);
}